// Round 1
// baseline (207.847 us; speedup 1.0000x reference)
//
#include <hip/hip_runtime.h>
#include <stdint.h>

#define V 128000
#define V4 (V / 4)
#define HV4 (V4 / 2)      // 16000 float4 per half-row
#define BROWS 256
#define CAP 2048          // legacy single-kernel capacity
#define CAP_HALF 2048     // per-half candidate capacity (expected ~87)
#define CAP2 4096         // merge-kernel capacity
#define NTHREADS 1024     // legacy single-kernel block
#define NT1 1024          // stream kernel block
#define NT2 256           // merge kernel block
#define T0 16.0f
#define THR0 6.0f

__device__ __forceinline__ unsigned rotl32(unsigned x, int d) {
  return (x << d) | (x >> (32 - d));
}

// JAX threefry2x32, key (0, 42) == jax.random.key(42).
// PARTITIONABLE path: counter = (0, i); 32-bit draw = XOR-fold. [verified]
__device__ __forceinline__ uint2 threefry2x32(unsigned x0, unsigned x1) {
  const unsigned k0 = 0u, k1 = 42u;
  const unsigned k2 = k0 ^ k1 ^ 0x1BD11BDAu;
  x0 += k0; x1 += k1;
#define TF_RND(r) { x0 += x1; x1 = rotl32(x1, r); x1 ^= x0; }
  TF_RND(13) TF_RND(15) TF_RND(26) TF_RND(6)
  x0 += k1; x1 += k2 + 1u;
  TF_RND(17) TF_RND(29) TF_RND(16) TF_RND(24)
  x0 += k2; x1 += k0 + 2u;
  TF_RND(13) TF_RND(15) TF_RND(26) TF_RND(6)
  x0 += k0; x1 += k1 + 3u;
  TF_RND(17) TF_RND(29) TF_RND(16) TF_RND(24)
  x0 += k1; x1 += k2 + 4u;
  TF_RND(13) TF_RND(15) TF_RND(26) TF_RND(6)
  x0 += k2; x1 += k0 + 5u;
#undef TF_RND
  return make_uint2(x0, x1);
}

__device__ __forceinline__ float gumbel_at(unsigned flat) {
  uint2 r = threefry2x32(0u, flat);
  unsigned bits = r.x ^ r.y;  // XOR fold
  float f = __uint_as_float((bits >> 9) | 0x3F800000u) - 1.0f;
  const float TINY = 1.17549435e-38f;
  float u = fmaxf(TINY, f + TINY);
  return -logf(-logf(u));
}

// monotone float -> uint mapping (total order, sign-robust)
__device__ __forceinline__ unsigned fkey(float v) {
  unsigned u = __float_as_uint(v);
  return (u & 0x80000000u) ? ~u : (u | 0x80000000u);
}
__device__ __forceinline__ float fkey_inv(unsigned u) {
  unsigned r = (u & 0x80000000u) ? (u & 0x7FFFFFFFu) : ~u;
  return __uint_as_float(r);
}

// ============================================================================
// Kernel 1: stream half a row.  512 blocks -> 2 blocks/CU -> 32 waves/CU.
// __launch_bounds__(1024, 8): force VGPR<=64 so 2 blocks co-reside per CU.
// Writes: partial Z, candidate count, candidate keys (value|~idx) to ws.
// ============================================================================
extern "C" __global__ void __launch_bounds__(NT1, 8)
stream_half_kernel(const float* __restrict__ logits,
                   float* __restrict__ wz,               // [BROWS*2]
                   int* __restrict__ wn,                 // [BROWS*2]
                   unsigned long long* __restrict__ wc)  // [BROWS*2][CAP_HALF]
{
  const int bid = blockIdx.x;
  const int b = bid >> 1;
  const int half = bid & 1;
  const int tid = threadIdx.x;

  __shared__ unsigned long long cand[CAP_HALF];
  __shared__ float zpart[NT1 / 64];
  __shared__ int cnt;

  if (tid == 0) cnt = 0;
  __syncthreads();

  const float4* row4 = (const float4*)(logits + (size_t)b * V);
  const float T = THR0;
  const float L2E = 1.44269504088896340736f;
  const float NB  = -16.0f * 1.44269504088896340736f;
  float zs0 = 0.0f, zs1 = 0.0f, zs2 = 0.0f, zs3 = 0.0f;

  const int beg = half * HV4;
  const int end = beg + HV4;

  // fmax gate: common case (no lane-elem above T) takes 1 branch per float4
  // instead of 4; per-element semantics inside are identical.
#define PROCV(vv, ii)                                                          \
  {                                                                            \
    float4 v = (vv);                                                           \
    zs0 += __builtin_amdgcn_exp2f(__builtin_fmaf(v.x, L2E, NB));               \
    zs1 += __builtin_amdgcn_exp2f(__builtin_fmaf(v.y, L2E, NB));               \
    zs2 += __builtin_amdgcn_exp2f(__builtin_fmaf(v.z, L2E, NB));               \
    zs3 += __builtin_amdgcn_exp2f(__builtin_fmaf(v.w, L2E, NB));               \
    float mx = fmaxf(fmaxf(v.x, v.y), fmaxf(v.z, v.w));                        \
    if (mx > T) {                                                              \
      int base = (ii) * 4;                                                     \
      if (v.x > T) { int pos = atomicAdd(&cnt, 1); if (pos < CAP_HALF) cand[pos] = ((unsigned long long)fkey(v.x) << 32) | (unsigned long long)(unsigned)(~(unsigned)(base + 0)); } \
      if (v.y > T) { int pos = atomicAdd(&cnt, 1); if (pos < CAP_HALF) cand[pos] = ((unsigned long long)fkey(v.y) << 32) | (unsigned long long)(unsigned)(~(unsigned)(base + 1)); } \
      if (v.z > T) { int pos = atomicAdd(&cnt, 1); if (pos < CAP_HALF) cand[pos] = ((unsigned long long)fkey(v.z) << 32) | (unsigned long long)(unsigned)(~(unsigned)(base + 2)); } \
      if (v.w > T) { int pos = atomicAdd(&cnt, 1); if (pos < CAP_HALF) cand[pos] = ((unsigned long long)fkey(v.w) << 32) | (unsigned long long)(unsigned)(~(unsigned)(base + 3)); } \
    }                                                                          \
  }

  {
    int i = beg + tid;
    for (; i + NT1 < end; i += 2 * NT1) {
      float4 a = row4[i];             // both loads in flight before first use
      float4 c = row4[i + NT1];
      PROCV(a, i);
      PROCV(c, i + NT1);
    }
    if (i < end) {
      float4 a = row4[i];
      PROCV(a, i);
    }
  }
#undef PROCV

  float s = zs0 + zs1 + zs2 + zs3;
#pragma unroll
  for (int off = 32; off > 0; off >>= 1) s += __shfl_down(s, off);
  if ((tid & 63) == 0) zpart[tid >> 6] = s;
  __syncthreads();

  if (tid == 0) {
    float z = 0.0f;
    for (int w = 0; w < NT1 / 64; ++w) z += zpart[w];
    wz[bid] = z;
    wn[bid] = cnt;   // raw count; merge kernel detects overflow
  }
  int m = cnt < CAP_HALF ? cnt : CAP_HALF;
  for (int j = tid; j < m; j += NT1) wc[(size_t)bid * CAP_HALF + j] = cand[j];
}

// ============================================================================
// Kernel 2: per row, merge the two halves' candidates, exact top-64 by rank
// counting (order-independent -> deterministic), then the verified epilogue.
// Fallback (never triggered on this data): full-row rescan with T adjust.
// ============================================================================
extern "C" __global__ void __launch_bounds__(NT2)
merge_sample_kernel(const float* __restrict__ logits,
                    const int* __restrict__ kin,
                    const float* __restrict__ pin,
                    const float* __restrict__ wz,
                    const int* __restrict__ wn,
                    const unsigned long long* __restrict__ wc,
                    int* __restrict__ out)
{
  const int b = blockIdx.x;
  const int tid = threadIdx.x;

  __shared__ unsigned long long cand[CAP2];
  __shared__ unsigned long long topkeys[64];
  __shared__ float sh_sp[64];
  __shared__ float sh_g[64];
  __shared__ int sh_idx[64];
  __shared__ int cnt;

  // fixed summation order -> deterministic Z
  const float Z = wz[2 * b] + wz[2 * b + 1];
  const int n0 = wn[2 * b];
  const int n1 = wn[2 * b + 1];
  const bool ok = (n0 <= CAP_HALF) && (n1 <= CAP_HALF);

  int N = 0;
  if (ok) {
    for (int j = tid; j < n0; j += NT2)
      cand[j] = wc[(size_t)(2 * b) * CAP_HALF + j];
    for (int j = tid; j < n1; j += NT2)
      cand[n0 + j] = wc[(size_t)(2 * b + 1) * CAP_HALF + j];
    N = n0 + n1;
  }
  __syncthreads();

  int n = ok ? N : (CAP2 + 1);   // uniform across block
  if (!(n >= 64 && n <= CAP2)) {
    // ---- fallback: rescan whole row with adjusted threshold
    const float4* row4 = (const float4*)(logits + (size_t)b * V);
    float T = THR0;
    int attempts = 0;
    while (!(n >= 64 && n <= CAP2) && attempts < 24) {
      T = (n < 64) ? (T - 2.0f) : (T + 1.0f);
      ++attempts;
      __syncthreads();
      if (tid == 0) cnt = 0;
      __syncthreads();
      for (int i = tid; i < V4; i += NT2) {
        float4 v = row4[i];
        int base = i * 4;
        if (v.x > T) { int pos = atomicAdd(&cnt, 1); if (pos < CAP2) cand[pos] = ((unsigned long long)fkey(v.x) << 32) | (unsigned long long)(unsigned)(~(unsigned)(base + 0)); }
        if (v.y > T) { int pos = atomicAdd(&cnt, 1); if (pos < CAP2) cand[pos] = ((unsigned long long)fkey(v.y) << 32) | (unsigned long long)(unsigned)(~(unsigned)(base + 1)); }
        if (v.z > T) { int pos = atomicAdd(&cnt, 1); if (pos < CAP2) cand[pos] = ((unsigned long long)fkey(v.z) << 32) | (unsigned long long)(unsigned)(~(unsigned)(base + 2)); }
        if (v.w > T) { int pos = atomicAdd(&cnt, 1); if (pos < CAP2) cand[pos] = ((unsigned long long)fkey(v.w) << 32) | (unsigned long long)(unsigned)(~(unsigned)(base + 3)); }
      }
      __syncthreads();
      n = cnt;
    }
    N = n < CAP2 ? n : CAP2;
  }
  __syncthreads();

  // ---- exact top-64 by (value desc, index asc) via rank counting
  for (int i = tid; i < N; i += NT2) {
    unsigned long long ki = cand[i];
    int rank = 0;
    for (int j = 0; j < N; ++j) rank += (cand[j] > ki) ? 1 : 0;
    if (rank < 64) topkeys[rank] = ki;
  }
  __syncthreads();

  const int M = N < 64 ? N : 64;

  // ---- per-rank prob + gumbel (rank r uses flat index b*V + r)
  if (tid < M) {
    unsigned long long key = topkeys[tid];
    float v = fkey_inv((unsigned)(key >> 32));
    sh_sp[tid] = expf(v - T0) / Z;
    sh_idx[tid] = (int)(~((unsigned)(key & 0xFFFFFFFFull)));
    sh_g[tid] = gumbel_at((unsigned)((size_t)b * V + tid));
  }
  __syncthreads();

  // ---- serial epilogue replicating reference float ops
  if (tid == 0) {
    int kk = kin[b];
    float pp = pin[b];
    float c = 0.0f, S = 0.0f;
    unsigned long long keepmask = 0ull;
    for (int r = 0; r < M; ++r) {
      float sp = sh_sp[r];
      c += sp;                         // inclusive cumsum, sequential fp32
      if (r < kk && (c - sp) < pp) {   // reference: (csum - sp) < p
        S += sp;
        keepmask |= (1ull << r);
      }
    }
    float best = -1e38f;
    int besti = sh_idx[0];
    for (int r = 0; r < M; ++r) {
      if (!(keepmask & (1ull << r))) continue;
      float lp = logf(fmaxf(sh_sp[r] / S, 1e-38f));
      float y = lp + sh_g[r];
      if (y > best) { best = y; besti = sh_idx[r]; }  // strict > = first occurrence
    }
    out[b] = besti;
  }
}

// ============================================================================
// Legacy single-kernel path (known-good, round-4 verified) — used only if the
// workspace is too small for the split pipeline.
// ============================================================================
extern "C" __global__ void __launch_bounds__(NTHREADS)
topk_topp_sample_kernel(const float* __restrict__ logits,
                        const int* __restrict__ kin,
                        const float* __restrict__ pin,
                        int* __restrict__ out) {
  const int b = blockIdx.x;
  const int tid = threadIdx.x;

  __shared__ unsigned long long cand[CAP];
  __shared__ unsigned long long topkeys[64];
  __shared__ float zpart[NTHREADS / 64];
  __shared__ float sh_sp[64];
  __shared__ float sh_g[64];
  __shared__ int sh_idx[64];
  __shared__ int cnt;
  __shared__ float shZ;

  const float4* row4 = (const float4*)(logits + (size_t)b * V);
  float T = THR0;

  if (tid == 0) cnt = 0;
  __syncthreads();

  const float L2E = 1.44269504088896340736f;
  const float NB  = -16.0f * 1.44269504088896340736f;
  float zs0 = 0.0f, zs1 = 0.0f;

#define PROCV1(vv, ii)                                                         \
  {                                                                            \
    float4 v = (vv);                                                           \
    zs0 += __builtin_amdgcn_exp2f(__builtin_fmaf(v.x, L2E, NB));               \
    zs1 += __builtin_amdgcn_exp2f(__builtin_fmaf(v.y, L2E, NB));               \
    zs0 += __builtin_amdgcn_exp2f(__builtin_fmaf(v.z, L2E, NB));               \
    zs1 += __builtin_amdgcn_exp2f(__builtin_fmaf(v.w, L2E, NB));               \
    int base = (ii) * 4;                                                       \
    if (v.x > T) { int pos = atomicAdd(&cnt, 1); if (pos < CAP) cand[pos] = ((unsigned long long)fkey(v.x) << 32) | (unsigned long long)(unsigned)(~(unsigned)(base + 0)); } \
    if (v.y > T) { int pos = atomicAdd(&cnt, 1); if (pos < CAP) cand[pos] = ((unsigned long long)fkey(v.y) << 32) | (unsigned long long)(unsigned)(~(unsigned)(base + 1)); } \
    if (v.z > T) { int pos = atomicAdd(&cnt, 1); if (pos < CAP) cand[pos] = ((unsigned long long)fkey(v.z) << 32) | (unsigned long long)(unsigned)(~(unsigned)(base + 2)); } \
    if (v.w > T) { int pos = atomicAdd(&cnt, 1); if (pos < CAP) cand[pos] = ((unsigned long long)fkey(v.w) << 32) | (unsigned long long)(unsigned)(~(unsigned)(base + 3)); } \
  }

  {
    int i = tid;
    for (; i + NTHREADS < V4; i += 2 * NTHREADS) {
      float4 a = row4[i];
      float4 c = row4[i + NTHREADS];
      PROCV1(a, i);
      PROCV1(c, i + NTHREADS);
    }
    if (i < V4) {
      float4 a = row4[i];
      PROCV1(a, i);
    }
  }
#undef PROCV1
  float s = zs0 + zs1;

#pragma unroll
  for (int off = 32; off > 0; off >>= 1) s += __shfl_down(s, off);
  if ((tid & 63) == 0) zpart[tid >> 6] = s;
  __syncthreads();
  if (tid == 0) {
    float z = 0.0f;
    for (int w = 0; w < NTHREADS / 64; ++w) z += zpart[w];
    shZ = z;
  }
  __syncthreads();

  int attempts = 0;
  while (true) {
    int n = cnt;
    if ((n >= 64 && n <= CAP) || attempts >= 24) break;
    T = (n < 64) ? (T - 2.0f) : (T + 1.0f);
    ++attempts;
    __syncthreads();
    if (tid == 0) cnt = 0;
    __syncthreads();
    for (int i = tid; i < V4; i += NTHREADS) {
      float4 v = row4[i];
      int base = i * 4;
      if (v.x > T) { int pos = atomicAdd(&cnt, 1); if (pos < CAP) cand[pos] = ((unsigned long long)fkey(v.x) << 32) | (unsigned long long)(unsigned)(~(unsigned)(base + 0)); }
      if (v.y > T) { int pos = atomicAdd(&cnt, 1); if (pos < CAP) cand[pos] = ((unsigned long long)fkey(v.y) << 32) | (unsigned long long)(unsigned)(~(unsigned)(base + 1)); }
      if (v.z > T) { int pos = atomicAdd(&cnt, 1); if (pos < CAP) cand[pos] = ((unsigned long long)fkey(v.z) << 32) | (unsigned long long)(unsigned)(~(unsigned)(base + 2)); }
      if (v.w > T) { int pos = atomicAdd(&cnt, 1); if (pos < CAP) cand[pos] = ((unsigned long long)fkey(v.w) << 32) | (unsigned long long)(unsigned)(~(unsigned)(base + 3)); }
    }
    __syncthreads();
  }

  int N = cnt < CAP ? cnt : CAP;

  for (int i = tid; i < N; i += NTHREADS) {
    unsigned long long ki = cand[i];
    int rank = 0;
    for (int j = 0; j < N; ++j) rank += (cand[j] > ki) ? 1 : 0;
    if (rank < 64) topkeys[rank] = ki;
  }
  __syncthreads();

  int M = N < 64 ? N : 64;

  if (tid < M) {
    unsigned long long key = topkeys[tid];
    float v = fkey_inv((unsigned)(key >> 32));
    sh_sp[tid] = expf(v - T0) / shZ;
    sh_idx[tid] = (int)(~((unsigned)(key & 0xFFFFFFFFull)));
    sh_g[tid] = gumbel_at((unsigned)((size_t)b * V + tid));
  }
  __syncthreads();

  if (tid == 0) {
    int kk = kin[b];
    float pp = pin[b];
    float c = 0.0f, S = 0.0f;
    unsigned long long keepmask = 0ull;
    for (int r = 0; r < M; ++r) {
      float sp = sh_sp[r];
      c += sp;
      if (r < kk && (c - sp) < pp) {
        S += sp;
        keepmask |= (1ull << r);
      }
    }
    float best = -1e38f;
    int besti = sh_idx[0];
    for (int r = 0; r < M; ++r) {
      if (!(keepmask & (1ull << r))) continue;
      float lp = logf(fmaxf(sh_sp[r] / S, 1e-38f));
      float y = lp + sh_g[r];
      if (y > best) { best = y; besti = sh_idx[r]; }
    }
    out[b] = besti;
  }
}

extern "C" void kernel_launch(void* const* d_in, const int* in_sizes, int n_in,
                              void* d_out, int out_size, void* d_ws, size_t ws_size,
                              hipStream_t stream) {
  const float* logits = (const float*)d_in[0];
  const int* k = (const int*)d_in[1];
  const float* p = (const float*)d_in[2];
  int* out = (int*)d_out;
  (void)in_sizes; (void)n_in; (void)out_size;

  // ws layout: [0..2KB) partial Z (512 f32) | [4KB..6KB) counts (512 i32)
  //            | [8KB .. 8KB+8MB) candidate keys (512 * CAP_HALF * u64)
  const size_t need = 8192 + (size_t)BROWS * 2 * CAP_HALF * 8;
  if (d_ws != nullptr && ws_size >= need) {
    float* wz = (float*)d_ws;
    int* wn = (int*)((char*)d_ws + 4096);
    unsigned long long* wc = (unsigned long long*)((char*)d_ws + 8192);
    stream_half_kernel<<<BROWS * 2, NT1, 0, stream>>>(logits, wz, wn, wc);
    merge_sample_kernel<<<BROWS, NT2, 0, stream>>>(logits, k, p, wz, wn, wc, out);
  } else {
    topk_topp_sample_kernel<<<BROWS, NTHREADS, 0, stream>>>(logits, k, p, out);
  }
}

// Round 2
// 202.014 us; speedup vs baseline: 1.0289x; 1.0289x over previous
//
#include <hip/hip_runtime.h>
#include <stdint.h>

#define V 128000
#define V4 (V / 4)
#define BROWS 256
#define CAP 2048
#define NTHREADS 1024
#define T0 16.0f

__device__ __forceinline__ unsigned rotl32(unsigned x, int d) {
  return (x << d) | (x >> (32 - d));
}

// JAX threefry2x32, key (0, 42) == jax.random.key(42).
// PARTITIONABLE path (default since JAX 0.4.30): counter = (0, i);
// 32-bit draw = XOR-fold of the two output words.  [verified: round 4 passed]
__device__ __forceinline__ uint2 threefry2x32(unsigned x0, unsigned x1) {
  const unsigned k0 = 0u, k1 = 42u;
  const unsigned k2 = k0 ^ k1 ^ 0x1BD11BDAu;
  x0 += k0; x1 += k1;
#define TF_RND(r) { x0 += x1; x1 = rotl32(x1, r); x1 ^= x0; }
  TF_RND(13) TF_RND(15) TF_RND(26) TF_RND(6)
  x0 += k1; x1 += k2 + 1u;
  TF_RND(17) TF_RND(29) TF_RND(16) TF_RND(24)
  x0 += k2; x1 += k0 + 2u;
  TF_RND(13) TF_RND(15) TF_RND(26) TF_RND(6)
  x0 += k0; x1 += k1 + 3u;
  TF_RND(17) TF_RND(29) TF_RND(16) TF_RND(24)
  x0 += k1; x1 += k2 + 4u;
  TF_RND(13) TF_RND(15) TF_RND(26) TF_RND(6)
  x0 += k2; x1 += k0 + 5u;
#undef TF_RND
  return make_uint2(x0, x1);
}

__device__ __forceinline__ float gumbel_at(unsigned flat) {
  uint2 r = threefry2x32(0u, flat);
  unsigned bits = r.x ^ r.y;  // XOR fold
  float f = __uint_as_float((bits >> 9) | 0x3F800000u) - 1.0f;
  const float TINY = 1.17549435e-38f;
  float u = fmaxf(TINY, f + TINY);
  return -logf(-logf(u));
}

// monotone float -> uint mapping (total order, sign-robust)
__device__ __forceinline__ unsigned fkey(float v) {
  unsigned u = __float_as_uint(v);
  return (u & 0x80000000u) ? ~u : (u | 0x80000000u);
}
__device__ __forceinline__ float fkey_inv(unsigned u) {
  unsigned r = (u & 0x80000000u) ? (u & 0x7FFFFFFFu) : ~u;
  return __uint_as_float(r);
}

extern "C" __global__ void __launch_bounds__(NTHREADS)
topk_topp_sample_kernel(const float* __restrict__ logits,
                        const int* __restrict__ kin,
                        const float* __restrict__ pin,
                        int* __restrict__ out) {
  const int b = blockIdx.x;
  const int tid = threadIdx.x;

  __shared__ unsigned long long cand[CAP];
  __shared__ unsigned long long topkeys[64];
  __shared__ float zpart[NTHREADS / 64];
  __shared__ float sh_sp[64];
  __shared__ float sh_g[64];
  __shared__ int sh_idx[64];
  __shared__ int cnt;
  __shared__ float shZ;

  const float4* row4 = (const float4*)(logits + (size_t)b * V);
  float T = 6.0f;  // 64th largest logit ~6.58; ~173 expected above 6.0

  if (tid == 0) cnt = 0;
  __syncthreads();

  // ---- streaming pass: Z via native v_exp_f32 (Z needs only ~3 digits:
  // it cancels in log(sp/S); top-p mask has >=2.5x slack) + candidate collect.
  const float L2E = 1.44269504088896340736f;
  const float NB  = -16.0f * 1.44269504088896340736f;
  float zs0 = 0.0f, zs1 = 0.0f;

#define PROCV(vv, ii)                                                          \
  {                                                                            \
    float4 v = (vv);                                                           \
    zs0 += __builtin_amdgcn_exp2f(__builtin_fmaf(v.x, L2E, NB));               \
    zs1 += __builtin_amdgcn_exp2f(__builtin_fmaf(v.y, L2E, NB));               \
    zs0 += __builtin_amdgcn_exp2f(__builtin_fmaf(v.z, L2E, NB));               \
    zs1 += __builtin_amdgcn_exp2f(__builtin_fmaf(v.w, L2E, NB));               \
    int base = (ii) * 4;                                                       \
    if (v.x > T) { int pos = atomicAdd(&cnt, 1); if (pos < CAP) cand[pos] = ((unsigned long long)fkey(v.x) << 32) | (unsigned long long)(unsigned)(~(unsigned)(base + 0)); } \
    if (v.y > T) { int pos = atomicAdd(&cnt, 1); if (pos < CAP) cand[pos] = ((unsigned long long)fkey(v.y) << 32) | (unsigned long long)(unsigned)(~(unsigned)(base + 1)); } \
    if (v.z > T) { int pos = atomicAdd(&cnt, 1); if (pos < CAP) cand[pos] = ((unsigned long long)fkey(v.z) << 32) | (unsigned long long)(unsigned)(~(unsigned)(base + 2)); } \
    if (v.w > T) { int pos = atomicAdd(&cnt, 1); if (pos < CAP) cand[pos] = ((unsigned long long)fkey(v.w) << 32) | (unsigned long long)(unsigned)(~(unsigned)(base + 3)); } \
  }

  {
    int i = tid;
    for (; i + NTHREADS < V4; i += 2 * NTHREADS) {
      float4 a = row4[i];               // both loads issued before first use
      float4 c = row4[i + NTHREADS];
      PROCV(a, i);
      PROCV(c, i + NTHREADS);
    }
    if (i < V4) {
      float4 a = row4[i];
      PROCV(a, i);
    }
  }
  float s = zs0 + zs1;

  // block-reduce Z
#pragma unroll
  for (int off = 32; off > 0; off >>= 1) s += __shfl_down(s, off);
  if ((tid & 63) == 0) zpart[tid >> 6] = s;
  __syncthreads();
  if (tid == 0) {
    float z = 0.0f;
    for (int w = 0; w < NTHREADS / 64; ++w) z += zpart[w];
    shZ = z;
  }
  __syncthreads();

  // ---- fallback: adjust threshold if candidate count out of [64, CAP]
  int attempts = 0;
  while (true) {
    int n = cnt;  // uniform across block: read after barrier
    if ((n >= 64 && n <= CAP) || attempts >= 24) break;
    T = (n < 64) ? (T - 2.0f) : (T + 1.0f);
    ++attempts;
    __syncthreads();
    if (tid == 0) cnt = 0;
    __syncthreads();
    for (int i = tid; i < V4; i += NTHREADS) {
      float4 v = row4[i];
      int base = i * 4;
      if (v.x > T) { int pos = atomicAdd(&cnt, 1); if (pos < CAP) cand[pos] = ((unsigned long long)fkey(v.x) << 32) | (unsigned long long)(unsigned)(~(unsigned)(base + 0)); }
      if (v.y > T) { int pos = atomicAdd(&cnt, 1); if (pos < CAP) cand[pos] = ((unsigned long long)fkey(v.y) << 32) | (unsigned long long)(unsigned)(~(unsigned)(base + 1)); }
      if (v.z > T) { int pos = atomicAdd(&cnt, 1); if (pos < CAP) cand[pos] = ((unsigned long long)fkey(v.z) << 32) | (unsigned long long)(unsigned)(~(unsigned)(base + 2)); }
      if (v.w > T) { int pos = atomicAdd(&cnt, 1); if (pos < CAP) cand[pos] = ((unsigned long long)fkey(v.w) << 32) | (unsigned long long)(unsigned)(~(unsigned)(base + 3)); }
    }
    __syncthreads();
  }

  int N = cnt < CAP ? cnt : CAP;

  // ---- exact top-64 by (value desc, index asc) via rank counting.
  for (int i = tid; i < N; i += NTHREADS) {
    unsigned long long ki = cand[i];
    int rank = 0;
    for (int j = 0; j < N; ++j) rank += (cand[j] > ki) ? 1 : 0;
    if (rank < 64) topkeys[rank] = ki;
  }
  __syncthreads();

  int M = N < 64 ? N : 64;

  // ---- per-rank prob + gumbel (rank r uses flat index b*V + r)
  // accurate expf here (64 calls, matches the passing round-4 epilogue)
  if (tid < M) {
    unsigned long long key = topkeys[tid];
    float v = fkey_inv((unsigned)(key >> 32));
    sh_sp[tid] = expf(v - T0) / shZ;
    sh_idx[tid] = (int)(~((unsigned)(key & 0xFFFFFFFFull)));
    sh_g[tid] = gumbel_at((unsigned)((size_t)b * V + tid));
  }
  __syncthreads();

  // ---- serial epilogue replicating reference float ops
  if (tid == 0) {
    int kk = kin[b];
    float pp = pin[b];
    float c = 0.0f, S = 0.0f;
    unsigned long long keepmask = 0ull;
    for (int r = 0; r < M; ++r) {
      float sp = sh_sp[r];
      c += sp;                         // inclusive cumsum, sequential fp32
      if (r < kk && (c - sp) < pp) {   // reference: (csum - sp) < p
        S += sp;
        keepmask |= (1ull << r);
      }
    }
    float best = -1e38f;
    int besti = sh_idx[0];
    for (int r = 0; r < M; ++r) {
      if (!(keepmask & (1ull << r))) continue;
      float lp = logf(fmaxf(sh_sp[r] / S, 1e-38f));
      float y = lp + sh_g[r];
      if (y > best) { best = y; besti = sh_idx[r]; }  // strict > = first occurrence
    }
    out[b] = besti;
  }
}

extern "C" void kernel_launch(void* const* d_in, const int* in_sizes, int n_in,
                              void* d_out, int out_size, void* d_ws, size_t ws_size,
                              hipStream_t stream) {
  const float* logits = (const float*)d_in[0];
  const int* k = (const int*)d_in[1];
  const float* p = (const float*)d_in[2];
  int* out = (int*)d_out;
  (void)in_sizes; (void)n_in; (void)out_size; (void)d_ws; (void)ws_size;
  topk_topp_sample_kernel<<<BROWS, NTHREADS, 0, stream>>>(logits, k, p, out);
}